// Round 6
// baseline (418.790 us; speedup 1.0000x reference)
//
#include <hip/hip_runtime.h>
#include <hip/hip_bf16.h>

#define BB 16
#define NI 2048
#define NA 2048
#define DD 256
#define KVB 32
#define NT (NA / KVB)   // 64

typedef _Float16 half8 __attribute__((ext_vector_type(8)));
typedef __attribute__((ext_vector_type(4))) float f32x4;

static __device__ __forceinline__ unsigned short f2h(float f) {
  union { _Float16 h; unsigned short u; } x; x.h = (_Float16)f; return x.u;
}
static __device__ __forceinline__ float h2f(unsigned short u) {
  union { _Float16 h; unsigned short u; } x; x.u = u; return (float)x.h;
}

// ---------------- prep: attendee -> kf16 (fp16 row-major) + vt (fp16, transposed) ----
__global__ void prep_kernel(const float* __restrict__ a,
                            unsigned short* __restrict__ kf16,
                            unsigned short* __restrict__ vt) {
  __shared__ float t[64][65];
  int bx = blockIdx.x;
  int b = bx >> 7;
  int r = bx & 127;
  int jt = r >> 2, dt = r & 3;
  int j0 = jt * 64, d0 = dt * 64;
  int tid = threadIdx.x;
  int rr = tid >> 4, c4 = tid & 15;
#pragma unroll
  for (int k = 0; k < 4; ++k) {
    int row = rr + k * 16;
    int j = j0 + row;
    float4 v = *(const float4*)(a + ((size_t)b * NA + j) * DD + d0 + c4 * 4);
    ushort4 hh;
    hh.x = f2h(v.x); hh.y = f2h(v.y); hh.z = f2h(v.z); hh.w = f2h(v.w);
    *(ushort4*)(kf16 + ((size_t)b * NA + j) * DD + d0 + c4 * 4) = hh;
    t[row][c4 * 4 + 0] = v.x; t[row][c4 * 4 + 1] = v.y;
    t[row][c4 * 4 + 2] = v.z; t[row][c4 * 4 + 3] = v.w;
  }
  __syncthreads();
#pragma unroll
  for (int k = 0; k < 4; ++k) {
    int d = rr + k * 16;
    ushort4 o;
    o.x = f2h(t[c4 * 4 + 0][d]); o.y = f2h(t[c4 * 4 + 1][d]);
    o.z = f2h(t[c4 * 4 + 2][d]); o.w = f2h(t[c4 * 4 + 3][d]);
    *(ushort4*)(vt + ((size_t)b * DD + d0 + d) * NA + j0 + c4 * 4) = o;
  }
}

// ---------------- tw: W -> W^T hi/lo fp16, row-XOR-swizzled [e][d] ----------------
__global__ void tw_kernel(const float* __restrict__ w,
                          unsigned short* __restrict__ wth,
                          unsigned short* __restrict__ wtl) {
  __shared__ float t[64][65];
  int bx = blockIdx.x;
  int dt = bx >> 2, et = bx & 3;
  int d0 = dt * 64, e0 = et * 64;
  int tid = threadIdx.x;
  int rr = tid >> 4, c4 = (tid & 15) * 4;
#pragma unroll
  for (int k = 0; k < 4; ++k) {
    int row = rr + k * 16;   // d index
    float4 v = *(const float4*)(w + (size_t)(d0 + row) * DD + e0 + c4);
    t[row][c4 + 0] = v.x; t[row][c4 + 1] = v.y; t[row][c4 + 2] = v.z; t[row][c4 + 3] = v.w;
  }
  __syncthreads();
#pragma unroll
  for (int k = 0; k < 4; ++k) {
    int e = rr + k * 16;
    int eg = e0 + e;
    ushort4 h, l;
    float v0 = t[c4 + 0][e]; h.x = f2h(v0); l.x = f2h(v0 - h2f(h.x));
    float v1 = t[c4 + 1][e]; h.y = f2h(v1); l.y = f2h(v1 - h2f(h.y));
    float v2 = t[c4 + 2][e]; h.z = f2h(v2); l.z = f2h(v2 - h2f(h.z));
    float v3 = t[c4 + 3][e]; h.w = f2h(v3); l.w = f2h(v3 - h2f(h.w));
    int dd = d0 + c4;
    int u = dd >> 3, sub = dd & 7;
    size_t off = (size_t)eg * DD + ((u ^ (eg & 7)) * 8) + sub;
    *(ushort4*)(wth + off) = h;
    *(ushort4*)(wtl + off) = l;
  }
}

// ---------------- Q = x @ W  (2-term fp16 MFMA), writes qf fp16 row-major ----------------
__global__ __launch_bounds__(256, 2) void qgemm_kernel(
    const float* __restrict__ x, const unsigned short* __restrict__ wth,
    const unsigned short* __restrict__ wtl, unsigned short* __restrict__ qf) {
  __shared__ unsigned short wb[2][64 * 256];   // 64 KB
  const int tid = threadIdx.x;
  const int lane = tid & 63;
  const int wv = tid >> 6;
  const int quad = lane >> 4;
  const int l16 = lane & 15;
  const int m0 = blockIdx.x * 64;

  half8 xf[8];
  {
    const float* xr = x + (size_t)(m0 + wv * 16 + l16) * DD;
#pragma unroll
    for (int c = 0; c < 8; ++c) {
      float4 a = *(const float4*)(xr + c * 32 + quad * 8);
      float4 b = *(const float4*)(xr + c * 32 + quad * 8 + 4);
      half8 v;
      v[0] = (_Float16)a.x; v[1] = (_Float16)a.y; v[2] = (_Float16)a.z; v[3] = (_Float16)a.w;
      v[4] = (_Float16)b.x; v[5] = (_Float16)b.y; v[6] = (_Float16)b.z; v[7] = (_Float16)b.w;
      xf[c] = v;
    }
  }

#pragma unroll 1
  for (int eg = 0; eg < 4; ++eg) {
    uint4 t0[8], t1[8];
    {
      const unsigned short* sh = wth + (size_t)(eg * 64) * DD;
      const unsigned short* sl = wtl + (size_t)(eg * 64) * DD;
#pragma unroll
      for (int i = 0; i < 8; ++i) {
        t0[i] = *(const uint4*)(sh + (i * 256 + tid) * 8);
        t1[i] = *(const uint4*)(sl + (i * 256 + tid) * 8);
      }
    }
    __syncthreads();
#pragma unroll
    for (int i = 0; i < 8; ++i) {
      *(uint4*)(wb[0] + (i * 256 + tid) * 8) = t0[i];
      *(uint4*)(wb[1] + (i * 256 + tid) * 8) = t1[i];
    }
    __syncthreads();
#pragma unroll
    for (int etl = 0; etl < 4; ++etl) {
      int rloc = etl * 16 + l16;
      f32x4 acc; acc[0] = acc[1] = acc[2] = acc[3] = 0.f;
#pragma unroll
      for (int c = 0; c < 8; ++c) {
        int off = rloc * DD + (((4 * c + quad) ^ (rloc & 7)) * 8);
        half8 wh = *(const half8*)(wb[0] + off);
        half8 wl = *(const half8*)(wb[1] + off);
        acc = __builtin_amdgcn_mfma_f32_16x16x32_f16(xf[c], wh, acc, 0, 0, 0);
        acc = __builtin_amdgcn_mfma_f32_16x16x32_f16(xf[c], wl, acc, 0, 0, 0);
      }
      int e = eg * 64 + etl * 16 + l16;
#pragma unroll
      for (int rg = 0; rg < 4; ++rg) {
        qf[(size_t)(m0 + wv * 16 + 4 * quad + rg) * DD + e] = f2h(acc[rg]);
      }
    }
  }
}

// ---------------- flash attention v6: barrier-free, K direct from L1/L2 ----------------
// 4 waves = 2 pairs x 2 d-halves; pair owns 32 q; both waves compute full 32x32 S^T
// (duplicated); PV splits d. K fragments loaded straight from global (L1-reused across
// the 4 waves of a block), in two 8-frag register batches. V direct from L2 after QK^T.
// LDS = wave-private P transpose only. Zero __syncthreads in the whole kernel.
__global__ __launch_bounds__(256, 2) void attn_kernel(
    const unsigned short* __restrict__ kf16, const unsigned short* __restrict__ vt,
    const unsigned short* __restrict__ qf, float* __restrict__ out) {
  __shared__ unsigned short pls[4][32 * 40];    // 10 KB (pad 40: ~2-way banks max)

  const int tid = threadIdx.x;
  const int lane = tid & 63;
  const int wv = tid >> 6;       // 0..3
  const int p = wv >> 1;         // pair
  const int h = wv & 1;          // d-half
  const int quad = lane >> 4;
  const int l16 = lane & 15;

  int bx = blockIdx.x;
  int lbx = (bx & 7) * 64 + (bx >> 3);   // XCD-chunked (512 = 8*64)
  const int b = lbx >> 5;
  const int qbase = (lbx & 31) * 64 + p * 32;

  const unsigned short* kb = kf16 + (size_t)b * NA * DD;
  const unsigned short* vb_base = vt + (size_t)b * (size_t)DD * NA + (size_t)(h * 128) * NA;

  // Q fragments (both q-tiles of the pair)
  half8 qh[2][8];
#pragma unroll
  for (int qt = 0; qt < 2; ++qt) {
    const size_t qrow = ((size_t)b * NI + qbase + qt * 16 + l16) * DD;
#pragma unroll
    for (int c = 0; c < 8; ++c)
      qh[qt][c] = *(const half8*)(qf + qrow + c * 32 + quad * 8);
  }

  f32x4 acc[2][8];
#pragma unroll
  for (int qt = 0; qt < 2; ++qt)
#pragma unroll
    for (int dt = 0; dt < 8; ++dt) { acc[qt][dt][0] = 0.f; acc[qt][dt][1] = 0.f; acc[qt][dt][2] = 0.f; acc[qt][dt][3] = 0.f; }
  float m0r = -INFINITY, m1r = -INFINITY;
  float l0 = 0.f, l1 = 0.f;    // per-lane partial denominators

  unsigned short* pw = pls[wv];
  const int krow0 = l16 * DD + quad * 8;         // jt=0 row offset
  const int krow1 = (16 + l16) * DD + quad * 8;  // jt=1 row offset

#pragma unroll 1
  for (int kt = 0; kt < NT; ++kt) {
    const int jb = kt * KVB;
    const unsigned short* ktile = kb + (size_t)jb * DD;

    // ---- K batch A (c=0..3) ----
    half8 ka[8];
#pragma unroll
    for (int c = 0; c < 4; ++c) {
      ka[c * 2 + 0] = *(const half8*)(ktile + krow0 + c * 32);
      ka[c * 2 + 1] = *(const half8*)(ktile + krow1 + c * 32);
    }
    // ---- K batch B (c=4..7) issued before consuming A ----
    half8 kbf[8];
#pragma unroll
    for (int c = 0; c < 4; ++c) {
      kbf[c * 2 + 0] = *(const half8*)(ktile + krow0 + (c + 4) * 32);
      kbf[c * 2 + 1] = *(const half8*)(ktile + krow1 + (c + 4) * 32);
    }

    // ---- QK^T: S^T[32 j x 32 q] ----
    f32x4 st[2][2];
    st[0][0][0]=st[0][0][1]=st[0][0][2]=st[0][0][3]=0.f;
    st[0][1][0]=st[0][1][1]=st[0][1][2]=st[0][1][3]=0.f;
    st[1][0][0]=st[1][0][1]=st[1][0][2]=st[1][0][3]=0.f;
    st[1][1][0]=st[1][1][1]=st[1][1][2]=st[1][1][3]=0.f;
#pragma unroll
    for (int c = 0; c < 4; ++c) {
#pragma unroll
      for (int jt = 0; jt < 2; ++jt) {
        st[0][jt] = __builtin_amdgcn_mfma_f32_16x16x32_f16(ka[c * 2 + jt], qh[0][c], st[0][jt], 0, 0, 0);
        st[1][jt] = __builtin_amdgcn_mfma_f32_16x16x32_f16(ka[c * 2 + jt], qh[1][c], st[1][jt], 0, 0, 0);
      }
    }
#pragma unroll
    for (int c = 0; c < 4; ++c) {
#pragma unroll
      for (int jt = 0; jt < 2; ++jt) {
        st[0][jt] = __builtin_amdgcn_mfma_f32_16x16x32_f16(kbf[c * 2 + jt], qh[0][c + 4], st[0][jt], 0, 0, 0);
        st[1][jt] = __builtin_amdgcn_mfma_f32_16x16x32_f16(kbf[c * 2 + jt], qh[1][c + 4], st[1][jt], 0, 0, 0);
      }
    }

    // ---- V loads (own d-half), covered by softmax below ----
    half8 vb[8];
#pragma unroll
    for (int dt = 0; dt < 8; ++dt)
      vb[dt] = *(const half8*)(vb_base + (size_t)(dt * 16 + l16) * NA + jb + quad * 8);

    // ---- per-wave softmax (lane owns row q=l16 across regs+quads) ----
    float mt0 = fmaxf(fmaxf(fmaxf(st[0][0][0], st[0][0][1]), fmaxf(st[0][0][2], st[0][0][3])),
                      fmaxf(fmaxf(st[0][1][0], st[0][1][1]), fmaxf(st[0][1][2], st[0][1][3])));
    float mt1 = fmaxf(fmaxf(fmaxf(st[1][0][0], st[1][0][1]), fmaxf(st[1][0][2], st[1][0][3])),
                      fmaxf(fmaxf(st[1][1][0], st[1][1][1]), fmaxf(st[1][1][2], st[1][1][3])));
    mt0 = fmaxf(mt0, __shfl_xor(mt0, 16)); mt0 = fmaxf(mt0, __shfl_xor(mt0, 32));
    mt1 = fmaxf(mt1, __shfl_xor(mt1, 16)); mt1 = fmaxf(mt1, __shfl_xor(mt1, 32));
    bool upd = __any((mt0 > m0r + 8.f) || (mt1 > m1r + 8.f)) != 0;
    if (upd) {
      float mn0 = fmaxf(m0r, mt0), mn1 = fmaxf(m1r, mt1);
      float sc0 = __expf(m0r - mn0), sc1 = __expf(m1r - mn1);
      l0 *= sc0; l1 *= sc1;
#pragma unroll
      for (int rg = 0; rg < 4; ++rg) {
        float a0 = __shfl(sc0, 4 * quad + rg);
        float a1 = __shfl(sc1, 4 * quad + rg);
#pragma unroll
        for (int dt = 0; dt < 8; ++dt) { acc[0][dt][rg] *= a0; acc[1][dt][rg] *= a1; }
      }
      m0r = mn0; m1r = mn1;
    }

    // ---- exp + per-lane partial sums + P write (wave-private LDS, no barrier) ----
    float e0[2][4], e1[2][4];
#pragma unroll
    for (int jt = 0; jt < 2; ++jt)
#pragma unroll
      for (int rg = 0; rg < 4; ++rg) {
        e0[jt][rg] = __expf(st[0][jt][rg] - m0r);
        e1[jt][rg] = __expf(st[1][jt][rg] - m1r);
      }
    l0 += ((e0[0][0] + e0[0][1]) + (e0[0][2] + e0[0][3])) +
          ((e0[1][0] + e0[1][1]) + (e0[1][2] + e0[1][3]));
    l1 += ((e1[0][0] + e1[0][1]) + (e1[0][2] + e1[0][3])) +
          ((e1[1][0] + e1[1][1]) + (e1[1][2] + e1[1][3]));
#pragma unroll
    for (int jt = 0; jt < 2; ++jt) {
      ushort4 pk;
      pk.x = f2h(e0[jt][0]); pk.y = f2h(e0[jt][1]); pk.z = f2h(e0[jt][2]); pk.w = f2h(e0[jt][3]);
      *(ushort4*)(pw + l16 * 40 + jt * 16 + quad * 4) = pk;
      pk.x = f2h(e1[jt][0]); pk.y = f2h(e1[jt][1]); pk.z = f2h(e1[jt][2]); pk.w = f2h(e1[jt][3]);
      *(ushort4*)(pw + (16 + l16) * 40 + jt * 16 + quad * 4) = pk;
    }
    half8 pa0 = *(const half8*)(pw + l16 * 40 + quad * 8);
    half8 pa1 = *(const half8*)(pw + (16 + l16) * 40 + quad * 8);

    // ---- PV (own d-half) ----
#pragma unroll
    for (int dt = 0; dt < 8; ++dt) {
      acc[0][dt] = __builtin_amdgcn_mfma_f32_16x16x32_f16(pa0, vb[dt], acc[0][dt], 0, 0, 0);
      acc[1][dt] = __builtin_amdgcn_mfma_f32_16x16x32_f16(pa1, vb[dt], acc[1][dt], 0, 0, 0);
    }
  }

  // ---- epilogue: reduce denominators, normalize, store ----
  l0 += __shfl_xor(l0, 16); l0 += __shfl_xor(l0, 32);
  l1 += __shfl_xor(l1, 16); l1 += __shfl_xor(l1, 32);
  float inv0 = 1.0f / l0, inv1 = 1.0f / l1;
  size_t ob = ((size_t)b * NI + qbase) * DD + h * 128;
#pragma unroll
  for (int rg = 0; rg < 4; ++rg) {
    float i0 = __shfl(inv0, 4 * quad + rg);
    float i1 = __shfl(inv1, 4 * quad + rg);
#pragma unroll
    for (int dt = 0; dt < 8; ++dt) {
      int d = dt * 16 + l16;
      out[ob + (size_t)(4 * quad + rg) * DD + d] = acc[0][dt][rg] * i0;
      out[ob + (size_t)(16 + 4 * quad + rg) * DD + d] = acc[1][dt][rg] * i1;
    }
  }
}

extern "C" void kernel_launch(void* const* d_in, const int* in_sizes, int n_in,
                              void* d_out, int out_size, void* d_ws, size_t ws_size,
                              hipStream_t stream) {
  const float* x = (const float*)d_in[0];        // [16,2048,256]
  const float* att = (const float*)d_in[1];      // [16,2048,256]
  const float* W = (const float*)d_in[2];        // [256,256]
  float* out = (float*)d_out;

  const size_t NE = (size_t)BB * NA * DD;        // 8388608
  unsigned short* w0   = (unsigned short*)d_ws;
  unsigned short* kf16 = w0;
  unsigned short* vtp  = w0 + NE;
  unsigned short* qfp  = w0 + 2 * NE;
  unsigned short* wth  = w0 + 3 * NE;
  unsigned short* wtl  = w0 + 3 * NE + (size_t)DD * DD;

  prep_kernel<<<2048, 256, 0, stream>>>(att, kf16, vtp);
  tw_kernel<<<16, 256, 0, stream>>>(W, wth, wtl);
  qgemm_kernel<<<512, 256, 0, stream>>>(x, wth, wtl, qfp);
  attn_kernel<<<512, 256, 0, stream>>>(kf16, vtp, qfp, out);
}

// Round 9
// 274.163 us; speedup vs baseline: 1.5275x; 1.5275x over previous
//
#include <hip/hip_runtime.h>
#include <hip/hip_bf16.h>

#define BB 16
#define NI 2048
#define NA 2048
#define DD 256
#define KVB 32
#define NT (NA / KVB)   // 64

typedef _Float16 half8 __attribute__((ext_vector_type(8)));
typedef __attribute__((ext_vector_type(4))) float f32x4;
typedef __attribute__((ext_vector_type(4))) unsigned int uint4v;

static __device__ __forceinline__ unsigned short f2h(float f) {
  union { _Float16 h; unsigned short u; } x; x.h = (_Float16)f; return x.u;
}
static __device__ __forceinline__ float h2f(unsigned short u) {
  union { _Float16 h; unsigned short u; } x; x.u = u; return (float)x.h;
}
static __device__ __forceinline__ unsigned int pk2(float a, float b) {
  return __builtin_bit_cast(unsigned int, __builtin_amdgcn_cvt_pkrtz(a, b));
}

// ---------------- prep: attendee -> kfrag + vfrag (fragment-ordered fp16) ----------------
// kfrag[b][kt][c(8)][jt(2)][lane(64)][e(8)]: lane=quad*16+l16 holds K[jb+jt*16+l16][c*32+quad*8+e]
// vfrag[b][kt][h(2)][dt(8)][lane(64)][e(8)]: lane holds V^T[h*128+dt*16+l16][jb + pi(quad,e)]
//   with pi(quad,e) = (e>>2)*16 + 4*quad + (e&3)  — matches P's natural post-QK^T layout,
//   so PV needs NO cross-lane P redistribution (dot-product is k-permutation invariant).
__global__ void prep_kernel(const float* __restrict__ a,
                            unsigned short* __restrict__ kfrag,
                            unsigned short* __restrict__ vfrag) {
  __shared__ float t[64][65];
  int bx = blockIdx.x;
  int b = bx >> 7;
  int r = bx & 127;
  int jt_t = r >> 2, dt_t = r & 3;
  int j0 = jt_t * 64, d0 = dt_t * 64;
  int tid = threadIdx.x;
  int rr = tid >> 4, c4 = tid & 15;
#pragma unroll
  for (int k = 0; k < 4; ++k) {
    int row = rr + k * 16;
    int j = j0 + row;
    int d = d0 + c4 * 4;
    float4 v = *(const float4*)(a + ((size_t)b * NA + j) * DD + d);
    ushort4 hh;
    hh.x = f2h(v.x); hh.y = f2h(v.y); hh.z = f2h(v.z); hh.w = f2h(v.w);
    int kt = j >> 5, jtf = (j >> 4) & 1, l16k = j & 15;
    int c = d >> 5, quad = (d >> 3) & 3, e = d & 7;
    *(ushort4*)(kfrag + ((size_t)b * NT + kt) * 8192 + c * 1024 + jtf * 512 +
                (quad * 16 + l16k) * 8 + e) = hh;
    t[row][c4 * 4 + 0] = v.x; t[row][c4 * 4 + 1] = v.y;
    t[row][c4 * 4 + 2] = v.z; t[row][c4 * 4 + 3] = v.w;
  }
  __syncthreads();
#pragma unroll
  for (int k = 0; k < 4; ++k) {
    int dl = rr + k * 16;
    int d = d0 + dl;
    int j = j0 + c4 * 4;              // 4 consecutive j
    ushort4 o;
    o.x = f2h(t[c4 * 4 + 0][dl]); o.y = f2h(t[c4 * 4 + 1][dl]);
    o.z = f2h(t[c4 * 4 + 2][dl]); o.w = f2h(t[c4 * 4 + 3][dl]);
    int kt = j >> 5;
    int quad = c4 & 3;                // pi-inverse: j=j0+4*c4+i -> quad=c4&3
    int jt = (c4 >> 2) & 1;           // e = jt*4 + i
    int hh_ = (d >> 7) & 1, dtl = (d >> 4) & 7, l16v = d & 15;
    *(ushort4*)(vfrag + ((size_t)b * NT + kt) * 8192 + hh_ * 4096 + dtl * 512 +
                (quad * 16 + l16v) * 8 + jt * 4) = o;
  }
}

// ---------------- tw: W -> W^T hi/lo fp16, row-XOR-swizzled [e][d] ----------------
__global__ void tw_kernel(const float* __restrict__ w,
                          unsigned short* __restrict__ wth,
                          unsigned short* __restrict__ wtl) {
  __shared__ float t[64][65];
  int bx = blockIdx.x;
  int dt = bx >> 2, et = bx & 3;
  int d0 = dt * 64, e0 = et * 64;
  int tid = threadIdx.x;
  int rr = tid >> 4, c4 = (tid & 15) * 4;
#pragma unroll
  for (int k = 0; k < 4; ++k) {
    int row = rr + k * 16;   // d index
    float4 v = *(const float4*)(w + (size_t)(d0 + row) * DD + e0 + c4);
    t[row][c4 + 0] = v.x; t[row][c4 + 1] = v.y; t[row][c4 + 2] = v.z; t[row][c4 + 3] = v.w;
  }
  __syncthreads();
#pragma unroll
  for (int k = 0; k < 4; ++k) {
    int e = rr + k * 16;
    int eg = e0 + e;
    ushort4 h, l;
    float v0 = t[c4 + 0][e]; h.x = f2h(v0); l.x = f2h(v0 - h2f(h.x));
    float v1 = t[c4 + 1][e]; h.y = f2h(v1); l.y = f2h(v1 - h2f(h.y));
    float v2 = t[c4 + 2][e]; h.z = f2h(v2); l.z = f2h(v2 - h2f(h.z));
    float v3 = t[c4 + 3][e]; h.w = f2h(v3); l.w = f2h(v3 - h2f(h.w));
    int dd = d0 + c4;
    int u = dd >> 3, sub = dd & 7;
    size_t off = (size_t)eg * DD + ((u ^ (eg & 7)) * 8) + sub;
    *(ushort4*)(wth + off) = h;
    *(ushort4*)(wtl + off) = l;
  }
}

// ---------------- Q = x @ W  (2-term fp16 MFMA), writes qf fp16 row-major ----------------
__global__ __launch_bounds__(256, 2) void qgemm_kernel(
    const float* __restrict__ x, const unsigned short* __restrict__ wth,
    const unsigned short* __restrict__ wtl, unsigned short* __restrict__ qf) {
  __shared__ unsigned short wb[2][64 * 256];   // 64 KB
  const int tid = threadIdx.x;
  const int lane = tid & 63;
  const int wv = tid >> 6;
  const int quad = lane >> 4;
  const int l16 = lane & 15;
  const int m0 = blockIdx.x * 64;

  half8 xf[8];
  {
    const float* xr = x + (size_t)(m0 + wv * 16 + l16) * DD;
#pragma unroll
    for (int c = 0; c < 8; ++c) {
      float4 a = *(const float4*)(xr + c * 32 + quad * 8);
      float4 b = *(const float4*)(xr + c * 32 + quad * 8 + 4);
      half8 v;
      v[0] = (_Float16)a.x; v[1] = (_Float16)a.y; v[2] = (_Float16)a.z; v[3] = (_Float16)a.w;
      v[4] = (_Float16)b.x; v[5] = (_Float16)b.y; v[6] = (_Float16)b.z; v[7] = (_Float16)b.w;
      xf[c] = v;
    }
  }

#pragma unroll 1
  for (int eg = 0; eg < 4; ++eg) {
    uint4 t0[8], t1[8];
    {
      const unsigned short* sh = wth + (size_t)(eg * 64) * DD;
      const unsigned short* sl = wtl + (size_t)(eg * 64) * DD;
#pragma unroll
      for (int i = 0; i < 8; ++i) {
        t0[i] = *(const uint4*)(sh + (i * 256 + tid) * 8);
        t1[i] = *(const uint4*)(sl + (i * 256 + tid) * 8);
      }
    }
    __syncthreads();
#pragma unroll
    for (int i = 0; i < 8; ++i) {
      *(uint4*)(wb[0] + (i * 256 + tid) * 8) = t0[i];
      *(uint4*)(wb[1] + (i * 256 + tid) * 8) = t1[i];
    }
    __syncthreads();
#pragma unroll
    for (int etl = 0; etl < 4; ++etl) {
      int rloc = etl * 16 + l16;
      f32x4 acc; acc[0] = acc[1] = acc[2] = acc[3] = 0.f;
#pragma unroll
      for (int c = 0; c < 8; ++c) {
        int off = rloc * DD + (((4 * c + quad) ^ (rloc & 7)) * 8);
        half8 wh = *(const half8*)(wb[0] + off);
        half8 wl = *(const half8*)(wb[1] + off);
        acc = __builtin_amdgcn_mfma_f32_16x16x32_f16(xf[c], wh, acc, 0, 0, 0);
        acc = __builtin_amdgcn_mfma_f32_16x16x32_f16(xf[c], wl, acc, 0, 0, 0);
      }
      int e = eg * 64 + etl * 16 + l16;
#pragma unroll
      for (int rg = 0; rg < 4; ++rg) {
        qf[(size_t)(m0 + wv * 16 + 4 * quad + rg) * DD + e] = f2h(acc[rg]);
      }
    }
  }
}

// ---------------- flash attention v8: v4 skeleton + fragment layouts + zero-shuffle PV ----------------
// 4 waves = 2 pairs x 2 d-halves; pair owns 32 q; both waves compute full 32x32 S^T.
// K double-buffered in LDS via linear copy of kfrag (contiguous, conflict-free reads).
// V coalesced from co-permuted vfrag; P's A-fragment is a direct in-register pack
// (k-permutation shared by P and V). One __syncthreads per kt.
__global__ __launch_bounds__(256, 2) void attn_kernel(
    const unsigned short* __restrict__ kfrag, const unsigned short* __restrict__ vfrag,
    const unsigned short* __restrict__ qf, float* __restrict__ out) {
  __shared__ unsigned short kls[2][KVB * DD];   // 2 x 16 KB

  const int tid = threadIdx.x;
  const int lane = tid & 63;
  const int wv = tid >> 6;       // 0..3
  const int p = wv >> 1;         // pair
  const int h = wv & 1;          // d-half
  const int quad = lane >> 4;
  const int l16 = lane & 15;

  int bx = blockIdx.x;
  int lbx = (bx & 7) * 64 + (bx >> 3);   // XCD-chunked (512 = 8*64)
  const int b = lbx >> 5;
  const int qbase = (lbx & 31) * 64 + p * 32;

  const unsigned short* kfb = kfrag + (size_t)b * NT * 8192;
  const unsigned short* vfb = vfrag + (size_t)b * NT * 8192 + h * 4096;

  // Q fragments (both q-tiles of the pair)
  half8 qh[2][8];
#pragma unroll
  for (int qt = 0; qt < 2; ++qt) {
    const size_t qrow = ((size_t)b * NI + qbase + qt * 16 + l16) * DD;
#pragma unroll
    for (int c = 0; c < 8; ++c)
      qh[qt][c] = *(const half8*)(qf + qrow + c * 32 + quad * 8);
  }

  f32x4 acc[2][8];
#pragma unroll
  for (int qt = 0; qt < 2; ++qt)
#pragma unroll
    for (int dt = 0; dt < 8; ++dt) { acc[qt][dt][0] = 0.f; acc[qt][dt][1] = 0.f; acc[qt][dt][2] = 0.f; acc[qt][dt][3] = 0.f; }
  float m0r = -INFINITY, m1r = -INFINITY;
  float l0 = 0.f, l1 = 0.f;    // per-lane partial denominators

  // prologue: stage K tile 0 (linear coalesced copy)
  {
    const unsigned short* s = kfb;
#pragma unroll
    for (int i = 0; i < 4; ++i)
      *(uint4*)(&kls[0][0] + i * 2048 + tid * 8) = *(const uint4*)(s + i * 2048 + tid * 8);
  }
  __syncthreads();

#pragma unroll 1
  for (int kt = 0; kt < NT; ++kt) {
    // ---- V loads (own d-half), fully coalesced, consumed in PV ----
    half8 vb[8];
#pragma unroll
    for (int dt = 0; dt < 8; ++dt)
      vb[dt] = *(const half8*)(vfb + (size_t)kt * 8192 + dt * 512 + lane * 8);

    // ---- K(kt+1) prefetch into regs (linear coalesced) ----
    uint4 kf[4];
    if (kt + 1 < NT) {
      const unsigned short* s = kfb + (size_t)(kt + 1) * 8192;
#pragma unroll
      for (int i = 0; i < 4; ++i)
        kf[i] = *(const uint4*)(s + i * 2048 + tid * 8);
    }

    // ---- QK^T: S^T[32 j x 32 q] from contiguous LDS frags ----
    const unsigned short* kb = &kls[kt & 1][0];
    f32x4 st[2][2];
    st[0][0][0]=st[0][0][1]=st[0][0][2]=st[0][0][3]=0.f;
    st[0][1][0]=st[0][1][1]=st[0][1][2]=st[0][1][3]=0.f;
    st[1][0][0]=st[1][0][1]=st[1][0][2]=st[1][0][3]=0.f;
    st[1][1][0]=st[1][1][1]=st[1][1][2]=st[1][1][3]=0.f;
#pragma unroll
    for (int c = 0; c < 8; ++c) {
      half8 k0 = *(const half8*)(kb + c * 1024 + lane * 8);         // jt=0
      half8 k1 = *(const half8*)(kb + c * 1024 + 512 + lane * 8);   // jt=1
      st[0][0] = __builtin_amdgcn_mfma_f32_16x16x32_f16(k0, qh[0][c], st[0][0], 0, 0, 0);
      st[1][0] = __builtin_amdgcn_mfma_f32_16x16x32_f16(k0, qh[1][c], st[1][0], 0, 0, 0);
      st[0][1] = __builtin_amdgcn_mfma_f32_16x16x32_f16(k1, qh[0][c], st[0][1], 0, 0, 0);
      st[1][1] = __builtin_amdgcn_mfma_f32_16x16x32_f16(k1, qh[1][c], st[1][1], 0, 0, 0);
    }

    // ---- per-wave softmax (lane holds P[q=l16][j=jt*16+4*quad+rg]) ----
    float mt0 = fmaxf(fmaxf(fmaxf(st[0][0][0], st[0][0][1]), fmaxf(st[0][0][2], st[0][0][3])),
                      fmaxf(fmaxf(st[0][1][0], st[0][1][1]), fmaxf(st[0][1][2], st[0][1][3])));
    float mt1 = fmaxf(fmaxf(fmaxf(st[1][0][0], st[1][0][1]), fmaxf(st[1][0][2], st[1][0][3])),
                      fmaxf(fmaxf(st[1][1][0], st[1][1][1]), fmaxf(st[1][1][2], st[1][1][3])));
    mt0 = fmaxf(mt0, __shfl_xor(mt0, 16)); mt0 = fmaxf(mt0, __shfl_xor(mt0, 32));
    mt1 = fmaxf(mt1, __shfl_xor(mt1, 16)); mt1 = fmaxf(mt1, __shfl_xor(mt1, 32));
    bool upd = __any((mt0 > m0r + 8.f) || (mt1 > m1r + 8.f)) != 0;
    if (upd) {
      float mn0 = fmaxf(m0r, mt0), mn1 = fmaxf(m1r, mt1);
      float sc0 = __expf(m0r - mn0), sc1 = __expf(m1r - mn1);
      l0 *= sc0; l1 *= sc1;
#pragma unroll
      for (int rg = 0; rg < 4; ++rg) {
        float a0 = __shfl(sc0, 4 * quad + rg);
        float a1 = __shfl(sc1, 4 * quad + rg);
#pragma unroll
        for (int dt = 0; dt < 8; ++dt) { acc[0][dt][rg] *= a0; acc[1][dt][rg] *= a1; }
      }
      m0r = mn0; m1r = mn1;
    }

    // ---- exp + per-lane partial sums ----
    float e0[2][4], e1[2][4];
#pragma unroll
    for (int jt = 0; jt < 2; ++jt)
#pragma unroll
      for (int rg = 0; rg < 4; ++rg) {
        e0[jt][rg] = __expf(st[0][jt][rg] - m0r);
        e1[jt][rg] = __expf(st[1][jt][rg] - m1r);
      }
    l0 += ((e0[0][0] + e0[0][1]) + (e0[0][2] + e0[0][3])) +
          ((e0[1][0] + e0[1][1]) + (e0[1][2] + e0[1][3]));
    l1 += ((e1[0][0] + e1[0][1]) + (e1[0][2] + e1[0][3])) +
          ((e1[1][0] + e1[1][1]) + (e1[1][2] + e1[1][3]));

    // ---- P A-fragment: direct in-register pack (k-slot quad*8+e -> j = (e>>2)*16+4*quad+(e&3),
    //      matching vfrag's co-permuted B-fragment; no cross-lane movement needed) ----
    half8 pa0, pa1;
    {
      uint4v pa0u = { pk2(e0[0][0], e0[0][1]), pk2(e0[0][2], e0[0][3]),
                      pk2(e0[1][0], e0[1][1]), pk2(e0[1][2], e0[1][3]) };
      uint4v pa1u = { pk2(e1[0][0], e1[0][1]), pk2(e1[0][2], e1[0][3]),
                      pk2(e1[1][0], e1[1][1]), pk2(e1[1][2], e1[1][3]) };
      pa0 = __builtin_bit_cast(half8, pa0u);
      pa1 = __builtin_bit_cast(half8, pa1u);
    }

    // ---- PV (own d-half) ----
#pragma unroll
    for (int dt = 0; dt < 8; ++dt) {
      acc[0][dt] = __builtin_amdgcn_mfma_f32_16x16x32_f16(pa0, vb[dt], acc[0][dt], 0, 0, 0);
      acc[1][dt] = __builtin_amdgcn_mfma_f32_16x16x32_f16(pa1, vb[dt], acc[1][dt], 0, 0, 0);
    }

    // ---- stage next K into other buffer (late: full-body latency cover) ----
    if (kt + 1 < NT) {
      unsigned short* d = &kls[(kt + 1) & 1][0];
#pragma unroll
      for (int i = 0; i < 4; ++i)
        *(uint4*)(d + i * 2048 + tid * 8) = kf[i];
    }
    __syncthreads();
  }

  // ---- epilogue: reduce denominators, normalize, store ----
  l0 += __shfl_xor(l0, 16); l0 += __shfl_xor(l0, 32);
  l1 += __shfl_xor(l1, 16); l1 += __shfl_xor(l1, 32);
  float inv0 = 1.0f / l0, inv1 = 1.0f / l1;
  size_t ob = ((size_t)b * NI + qbase) * DD + h * 128;
#pragma unroll
  for (int rg = 0; rg < 4; ++rg) {
    float i0 = __shfl(inv0, 4 * quad + rg);
    float i1 = __shfl(inv1, 4 * quad + rg);
#pragma unroll
    for (int dt = 0; dt < 8; ++dt) {
      int d = dt * 16 + l16;
      out[ob + (size_t)(4 * quad + rg) * DD + d] = acc[0][dt][rg] * i0;
      out[ob + (size_t)(16 + 4 * quad + rg) * DD + d] = acc[1][dt][rg] * i1;
    }
  }
}

extern "C" void kernel_launch(void* const* d_in, const int* in_sizes, int n_in,
                              void* d_out, int out_size, void* d_ws, size_t ws_size,
                              hipStream_t stream) {
  const float* x = (const float*)d_in[0];        // [16,2048,256]
  const float* att = (const float*)d_in[1];      // [16,2048,256]
  const float* W = (const float*)d_in[2];        // [256,256]
  float* out = (float*)d_out;

  const size_t NE = (size_t)BB * NA * DD;        // 8388608
  unsigned short* w0    = (unsigned short*)d_ws;
  unsigned short* kfrag = w0;
  unsigned short* vfrag = w0 + NE;
  unsigned short* qfp   = w0 + 2 * NE;
  unsigned short* wth   = w0 + 3 * NE;
  unsigned short* wtl   = w0 + 3 * NE + (size_t)DD * DD;

  prep_kernel<<<2048, 256, 0, stream>>>(att, kfrag, vfrag);
  tw_kernel<<<16, 256, 0, stream>>>(W, wth, wtl);
  qgemm_kernel<<<512, 256, 0, stream>>>(x, wth, wtl, qfp);
  attn_kernel<<<512, 256, 0, stream>>>(kfrag, vfrag, qfp, out);
}